// Round 1
// baseline (104.021 us; speedup 1.0000x reference)
//
#include <hip/hip_runtime.h>

#define HW_PIX 114688   // 256*448
#define W_IMG  448
#define C_CH   64
#define NCAM   6
#define NCELL  28800    // 240*120
#define ZL     6
#define LVOX   172800   // ZL*NCELL

// ---------------------------------------------------------------------------
// Pass 1: transpose per-camera feature planes  [C][HW] -> [HW][C]  (f32)
// Block = 256 threads handles a 64-channel x 64-pixel tile through LDS.
// ---------------------------------------------------------------------------
__global__ __launch_bounds__(256) void vp_transpose_kernel(
    const float* __restrict__ fish, const float* __restrict__ pv,
    const float* __restrict__ front, float* __restrict__ featsT)
{
    const int tilesPerCam = HW_PIX / 64;            // 1792
    const int bid  = blockIdx.x;
    const int cam  = bid / tilesPerCam;
    const int pix0 = (bid % tilesPerCam) * 64;

    const float* src = (cam < 4) ? (fish + (size_t)cam * C_CH * HW_PIX)
                                 : ((cam == 4) ? pv : front);

    __shared__ float t[64][65];                     // +1 pad: no bank conflicts
    const int tid = threadIdx.x;

    // Load: 64 channel-rows x 16 float4 (64 px) each, coalesced along pixels.
    #pragma unroll
    for (int i = 0; i < 4; ++i) {
        int e   = i * 256 + tid;                    // 0..1023
        int c   = e >> 4;                           // 0..63
        int px4 = e & 15;                           // 0..15
        const float4 f = *reinterpret_cast<const float4*>(
            src + (size_t)c * HW_PIX + pix0 + px4 * 4);
        t[c][px4 * 4 + 0] = f.x;
        t[c][px4 * 4 + 1] = f.y;
        t[c][px4 * 4 + 2] = f.z;
        t[c][px4 * 4 + 3] = f.w;
    }
    __syncthreads();

    // Store: per pixel, 64 contiguous channels; 16 lanes x float4 = 256B rows.
    float* dst = featsT + ((size_t)cam * HW_PIX + pix0) * C_CH;
    #pragma unroll
    for (int i = 0; i < 4; ++i) {
        int e  = i * 256 + tid;
        int px = e >> 4;                            // 0..63
        int cg = e & 15;                            // channel group of 4
        float4 f;
        f.x = t[cg * 4 + 0][px];
        f.y = t[cg * 4 + 1][px];
        f.z = t[cg * 4 + 2][px];
        f.w = t[cg * 4 + 3][px];
        *reinterpret_cast<float4*>(dst + (size_t)px * C_CH + cg * 4) = f;
    }
}

// ---------------------------------------------------------------------------
// Pass 2: gather + weight + z-sum + coalesced write.
// Block = (cam, 64-cell tile). 256 threads = 16 groups x 16 lanes.
// Group g owns cells {g, g+16, g+32, g+48}; lane owns 4 channels (float4).
// All z for a given cell land in the same group -> race-free reg accumulate.
// ---------------------------------------------------------------------------
__global__ __launch_bounds__(256) void vp_gather_kernel(
    const float* __restrict__ featsT,
    const int*   __restrict__ uu, const int* __restrict__ vv,
    const int*   __restrict__ valid, const float* __restrict__ density,
    float* __restrict__ out)
{
    const int bid   = blockIdx.x;                   // 0..2699
    const int cam   = bid / (NCELL / 64);
    const int cell0 = (bid % (NCELL / 64)) * 64;
    const int tid   = threadIdx.x;

    __shared__ int   p_s[ZL * 64];                  // 384 pixel indices
    __shared__ float w_s[ZL * 64];                  // 384 weights
    __shared__ float acc_s[64][65];                 // [cell][channel], padded

    // Preload per-voxel pixel index + weight (coalesced, 64-wide per z-row).
    for (int v = tid; v < ZL * 64; v += 256) {
        int z  = v >> 6;
        int cl = v & 63;
        size_t l = (size_t)cam * LVOX + (size_t)z * NCELL + cell0 + cl;
        p_s[v] = vv[l] * W_IMG + uu[l];
        w_s[v] = valid[l] ? density[l] : 0.0f;
    }
    __syncthreads();

    const int g    = tid >> 4;                      // group 0..15
    const int lane = tid & 15;                      // channel group 0..15
    const float* base = featsT + (size_t)cam * HW_PIX * C_CH + lane * 4;

    float4 acc[4];
    #pragma unroll
    for (int ci = 0; ci < 4; ++ci) acc[ci] = make_float4(0.f, 0.f, 0.f, 0.f);

    #pragma unroll
    for (int ci = 0; ci < 4; ++ci) {
        const int cl = g + ci * 16;
        #pragma unroll
        for (int z = 0; z < ZL; ++z) {
            const int v = z * 64 + cl;
            const float w = w_s[v];
            if (w != 0.0f) {                        // skip ~50% invalid voxels
                const float4 f = *reinterpret_cast<const float4*>(
                    base + (size_t)p_s[v] * C_CH);
                acc[ci].x += f.x * w;
                acc[ci].y += f.y * w;
                acc[ci].z += f.z * w;
                acc[ci].w += f.w * w;
            }
        }
    }

    // Stage accumulators to LDS for a coalesced channel-major write.
    #pragma unroll
    for (int ci = 0; ci < 4; ++ci) {
        const int cl = g + ci * 16;
        acc_s[cl][lane * 4 + 0] = acc[ci].x;
        acc_s[cl][lane * 4 + 1] = acc[ci].y;
        acc_s[cl][lane * 4 + 2] = acc[ci].z;
        acc_s[cl][lane * 4 + 3] = acc[ci].w;
    }
    __syncthreads();

    // out[(cam*64 + c)*NCELL + cell0 + cl], float4 over cells: coalesced.
    #pragma unroll
    for (int i = 0; i < 4; ++i) {
        int e   = i * 256 + tid;                    // 0..1023
        int c   = e >> 4;                           // channel 0..63
        int cl4 = e & 15;                           // cell quad 0..15
        float4 f;
        f.x = acc_s[cl4 * 4 + 0][c];
        f.y = acc_s[cl4 * 4 + 1][c];
        f.z = acc_s[cl4 * 4 + 2][c];
        f.w = acc_s[cl4 * 4 + 3][c];
        *reinterpret_cast<float4*>(
            out + ((size_t)cam * C_CH + c) * NCELL + cell0 + cl4 * 4) = f;
    }
}

// ---------------------------------------------------------------------------
// Fallback (if d_ws too small for the transposed features): direct strided
// gather from the native layout. Correct but slower.
// ---------------------------------------------------------------------------
__global__ __launch_bounds__(256) void vp_fallback_kernel(
    const float* __restrict__ fish, const float* __restrict__ pv,
    const float* __restrict__ front,
    const int*   __restrict__ uu, const int* __restrict__ vv,
    const int*   __restrict__ valid, const float* __restrict__ density,
    float* __restrict__ out)
{
    const int idx = blockIdx.x * 256 + threadIdx.x;
    if (idx >= NCAM * C_CH * NCELL) return;
    const int cell = idx % NCELL;
    const int c    = (idx / NCELL) % C_CH;
    const int cam  = idx / (NCELL * C_CH);
    const float* src = (cam < 4)
        ? (fish + ((size_t)cam * C_CH + c) * HW_PIX)
        : (((cam == 4) ? pv : front) + (size_t)c * HW_PIX);
    float acc = 0.0f;
    for (int z = 0; z < ZL; ++z) {
        const size_t l = (size_t)cam * LVOX + (size_t)z * NCELL + cell;
        if (valid[l]) {
            acc += src[vv[l] * W_IMG + uu[l]] * density[l];
        }
    }
    out[idx] = acc;
}

extern "C" void kernel_launch(void* const* d_in, const int* in_sizes, int n_in,
                              void* d_out, int out_size, void* d_ws, size_t ws_size,
                              hipStream_t stream) {
    const float* fish    = (const float*)d_in[0];
    const float* pv      = (const float*)d_in[1];
    const float* front   = (const float*)d_in[2];
    const int*   uu      = (const int*)d_in[3];
    const int*   vv      = (const int*)d_in[4];
    const int*   valid   = (const int*)d_in[5];
    const float* density = (const float*)d_in[6];
    float*       out     = (float*)d_out;

    const size_t need = (size_t)NCAM * HW_PIX * C_CH * sizeof(float); // 168 MiB

    if (ws_size >= need) {
        float* featsT = (float*)d_ws;
        vp_transpose_kernel<<<NCAM * (HW_PIX / 64), 256, 0, stream>>>(
            fish, pv, front, featsT);
        vp_gather_kernel<<<NCAM * (NCELL / 64), 256, 0, stream>>>(
            featsT, uu, vv, valid, density, out);
    } else {
        vp_fallback_kernel<<<(NCAM * C_CH * NCELL + 255) / 256, 256, 0, stream>>>(
            fish, pv, front, uu, vv, valid, density, out);
    }
}

// Round 2
// 74.618 us; speedup vs baseline: 1.3940x; 1.3940x over previous
//
#include <hip/hip_runtime.h>

#define HW_PIX 114688   // 256*448
#define W_IMG  448
#define C_CH   64
#define NCAM   6
#define NCELL  28800    // 240*120
#define ZL     6
#define LVOX   172800   // ZL*NCELL

typedef unsigned int  uint32;
typedef unsigned short ushort16_t;

// bf16 round-to-nearest-even from f32
static __device__ __forceinline__ unsigned short f2bf(float x) {
    unsigned int u = __float_as_uint(x);
    unsigned int r = u + 0x7FFF + ((u >> 16) & 1);
    return (unsigned short)(r >> 16);
}
static __device__ __forceinline__ unsigned int pack2(float lo, float hi) {
    return (unsigned int)f2bf(lo) | ((unsigned int)f2bf(hi) << 16);
}

// ---------------------------------------------------------------------------
// Pass 1: transpose per-camera feature planes  [C][HW] (f32) -> [HW][C] (bf16)
// Block = 256 threads handles a 64-channel x 64-pixel tile through LDS.
// ---------------------------------------------------------------------------
__global__ __launch_bounds__(256) void vp_transpose_kernel(
    const float* __restrict__ fish, const float* __restrict__ pv,
    const float* __restrict__ front, unsigned short* __restrict__ featsT)
{
    const int tilesPerCam = HW_PIX / 64;            // 1792
    const int bid  = blockIdx.x;
    const int cam  = bid / tilesPerCam;
    const int pix0 = (bid % tilesPerCam) * 64;

    const float* src = (cam < 4) ? (fish + (size_t)cam * C_CH * HW_PIX)
                                 : ((cam == 4) ? pv : front);

    __shared__ float t[64][65];                     // +1 pad: no bank conflicts
    const int tid = threadIdx.x;

    // Load: 64 channel-rows x 16 float4 (64 px) each, coalesced along pixels.
    #pragma unroll
    for (int i = 0; i < 4; ++i) {
        int e   = i * 256 + tid;                    // 0..1023
        int c   = e >> 4;                           // 0..63
        int px4 = e & 15;                           // 0..15
        const float4 f = *reinterpret_cast<const float4*>(
            src + (size_t)c * HW_PIX + pix0 + px4 * 4);
        t[c][px4 * 4 + 0] = f.x;
        t[c][px4 * 4 + 1] = f.y;
        t[c][px4 * 4 + 2] = f.z;
        t[c][px4 * 4 + 3] = f.w;
    }
    __syncthreads();

    // Store: per pixel, 64 contiguous bf16 channels (128B); 8 groups x uint4.
    unsigned short* dst = featsT + ((size_t)cam * HW_PIX + pix0) * C_CH;
    #pragma unroll
    for (int i = 0; i < 2; ++i) {
        int e  = i * 256 + tid;                     // 0..511
        int px = e >> 3;                            // 0..63
        int cg = e & 7;                             // channel group of 8
        uint4 o;
        o.x = pack2(t[cg * 8 + 0][px], t[cg * 8 + 1][px]);
        o.y = pack2(t[cg * 8 + 2][px], t[cg * 8 + 3][px]);
        o.z = pack2(t[cg * 8 + 4][px], t[cg * 8 + 5][px]);
        o.w = pack2(t[cg * 8 + 6][px], t[cg * 8 + 7][px]);
        *reinterpret_cast<uint4*>(dst + (size_t)px * C_CH + cg * 8) = o;
    }
}

// ---------------------------------------------------------------------------
// Pass 2: gather (bf16) + weight + z-sum + coalesced f32 write.
// Block = (cam, 64-cell tile). 256 threads = 32 groups x 8 lanes.
// Group g owns cells {g, g+32}; lane owns 8 channels (one uint4 = 8 bf16).
// ---------------------------------------------------------------------------
__global__ __launch_bounds__(256) void vp_gather_kernel(
    const unsigned short* __restrict__ featsT,
    const int*   __restrict__ uu, const int* __restrict__ vv,
    const int*   __restrict__ valid, const float* __restrict__ density,
    float* __restrict__ out)
{
    const int bid   = blockIdx.x;                   // 0..2699
    const int cam   = bid / (NCELL / 64);
    const int cell0 = (bid % (NCELL / 64)) * 64;
    const int tid   = threadIdx.x;

    __shared__ int   p_s[ZL * 64];                  // 384 pixel indices
    __shared__ float w_s[ZL * 64];                  // 384 weights
    __shared__ float acc_s[64][65];                 // [cell][channel], padded

    // Preload per-voxel pixel index + weight (coalesced, 64-wide per z-row).
    for (int v = tid; v < ZL * 64; v += 256) {
        int z  = v >> 6;
        int cl = v & 63;
        size_t l = (size_t)cam * LVOX + (size_t)z * NCELL + cell0 + cl;
        p_s[v] = vv[l] * W_IMG + uu[l];
        w_s[v] = valid[l] ? density[l] : 0.0f;
    }
    __syncthreads();

    const int g    = tid >> 3;                      // group 0..31
    const int lane = tid & 7;                       // 8-ch group 0..7
    const unsigned short* base =
        featsT + (size_t)cam * HW_PIX * C_CH + lane * 8;

    float acc[2][8];
    #pragma unroll
    for (int ci = 0; ci < 2; ++ci)
        #pragma unroll
        for (int k = 0; k < 8; ++k) acc[ci][k] = 0.0f;

    #pragma unroll
    for (int ci = 0; ci < 2; ++ci) {
        const int cl = g + ci * 32;
        #pragma unroll
        for (int z = 0; z < ZL; ++z) {
            const int v = z * 64 + cl;
            const float w = w_s[v];
            if (w != 0.0f) {                        // skip ~50% invalid voxels
                const uint4 q = *reinterpret_cast<const uint4*>(
                    base + (size_t)p_s[v] * C_CH);
                acc[ci][0] += __uint_as_float(q.x << 16) * w;
                acc[ci][1] += __uint_as_float(q.x & 0xffff0000u) * w;
                acc[ci][2] += __uint_as_float(q.y << 16) * w;
                acc[ci][3] += __uint_as_float(q.y & 0xffff0000u) * w;
                acc[ci][4] += __uint_as_float(q.z << 16) * w;
                acc[ci][5] += __uint_as_float(q.z & 0xffff0000u) * w;
                acc[ci][6] += __uint_as_float(q.w << 16) * w;
                acc[ci][7] += __uint_as_float(q.w & 0xffff0000u) * w;
            }
        }
    }

    // Stage accumulators to LDS for a coalesced channel-major write.
    #pragma unroll
    for (int ci = 0; ci < 2; ++ci) {
        const int cl = g + ci * 32;
        #pragma unroll
        for (int k = 0; k < 8; ++k)
            acc_s[cl][lane * 8 + k] = acc[ci][k];
    }
    __syncthreads();

    // out[(cam*64 + c)*NCELL + cell0 + cl], float4 over cells: coalesced.
    #pragma unroll
    for (int i = 0; i < 4; ++i) {
        int e   = i * 256 + tid;                    // 0..1023
        int c   = e >> 4;                           // channel 0..63
        int cl4 = e & 15;                           // cell quad 0..15
        float4 f;
        f.x = acc_s[cl4 * 4 + 0][c];
        f.y = acc_s[cl4 * 4 + 1][c];
        f.z = acc_s[cl4 * 4 + 2][c];
        f.w = acc_s[cl4 * 4 + 3][c];
        *reinterpret_cast<float4*>(
            out + ((size_t)cam * C_CH + c) * NCELL + cell0 + cl4 * 4) = f;
    }
}

// ---------------------------------------------------------------------------
// Fallback (if d_ws too small): direct strided gather from native layout.
// ---------------------------------------------------------------------------
__global__ __launch_bounds__(256) void vp_fallback_kernel(
    const float* __restrict__ fish, const float* __restrict__ pv,
    const float* __restrict__ front,
    const int*   __restrict__ uu, const int* __restrict__ vv,
    const int*   __restrict__ valid, const float* __restrict__ density,
    float* __restrict__ out)
{
    const int idx = blockIdx.x * 256 + threadIdx.x;
    if (idx >= NCAM * C_CH * NCELL) return;
    const int cell = idx % NCELL;
    const int c    = (idx / NCELL) % C_CH;
    const int cam  = idx / (NCELL * C_CH);
    const float* src = (cam < 4)
        ? (fish + ((size_t)cam * C_CH + c) * HW_PIX)
        : (((cam == 4) ? pv : front) + (size_t)c * HW_PIX);
    float acc = 0.0f;
    for (int z = 0; z < ZL; ++z) {
        const size_t l = (size_t)cam * LVOX + (size_t)z * NCELL + cell;
        if (valid[l]) {
            acc += src[vv[l] * W_IMG + uu[l]] * density[l];
        }
    }
    out[idx] = acc;
}

extern "C" void kernel_launch(void* const* d_in, const int* in_sizes, int n_in,
                              void* d_out, int out_size, void* d_ws, size_t ws_size,
                              hipStream_t stream) {
    const float* fish    = (const float*)d_in[0];
    const float* pv      = (const float*)d_in[1];
    const float* front   = (const float*)d_in[2];
    const int*   uu      = (const int*)d_in[3];
    const int*   vv      = (const int*)d_in[4];
    const int*   valid   = (const int*)d_in[5];
    const float* density = (const float*)d_in[6];
    float*       out     = (float*)d_out;

    const size_t need = (size_t)NCAM * HW_PIX * C_CH * sizeof(unsigned short); // 84 MiB

    if (ws_size >= need) {
        unsigned short* featsT = (unsigned short*)d_ws;
        vp_transpose_kernel<<<NCAM * (HW_PIX / 64), 256, 0, stream>>>(
            fish, pv, front, featsT);
        vp_gather_kernel<<<NCAM * (NCELL / 64), 256, 0, stream>>>(
            featsT, uu, vv, valid, density, out);
    } else {
        vp_fallback_kernel<<<(NCAM * C_CH * NCELL + 255) / 256, 256, 0, stream>>>(
            fish, pv, front, uu, vv, valid, density, out);
    }
}